// Round 7
// baseline (556.513 us; speedup 1.0000x reference)
//
#include <hip/hip_runtime.h>
#include <hip/hip_bf16.h>

// MoE block: N=8192, D=1024, H=1024, E=16, top-k=2. Inputs fp32, output fp32.
// out[n] = w1*(x@W_e1 + b_e1) + w2*(x@W_e2 + b_e2), w = top-2 of softmax.
//
// Round-7:
//  * router: register-only coalesced scheme. lane=(e,chunk); per-lane fp64
//    partial dot (4 chains); shfl_xor reduce; top-2 on fp64 logits (same
//    comparison logic as r4/r5); softmax weights via fp32 __expf.
//    No LDS, low VGPR -> high occupancy. (r5: 165us gather-bound; r6: 197us
//    occupancy-bound; predicted ~12us.)
//  * GEMM fast path (ws >= 56 MB): r5's proven 128x128/BK32 geometry (~2
//    blocks/CU) but staging from pre-cast bf16 xb + transposed wt -> pure
//    b128 copy staging, no cvt VALU in the K-loop.
//  * fallback (small ws): r5 fp32-staging MFMA kernel, unchanged.

#define N_TOK 8192
#define D_DIM 1024
#define H_DIM 1024
#define E_NUM 16
#define CAP   1024
#define KPAD  40    // LDS row stride in ushorts (80 B)

typedef __attribute__((ext_vector_type(4))) float f32x4;
typedef __attribute__((ext_vector_type(8))) short bf16x8;

__device__ __forceinline__ unsigned short f2bf(float f) {
    unsigned int u = __float_as_uint(f);
    unsigned int r = u + 0x7fffu + ((u >> 16) & 1u);   // RNE
    return (unsigned short)(r >> 16);
}
__device__ __forceinline__ unsigned int pk2bf(float lo, float hi) {
    return (unsigned int)f2bf(lo) | ((unsigned int)f2bf(hi) << 16);
}

// ---------------- router: 256 blocks x 256 thr, 8 tokens/wave --------------
__global__ __launch_bounds__(256) void router_kernel(
    const float* __restrict__ x,
    const float* __restrict__ rw,
    const float* __restrict__ rb,
    int* __restrict__ counts0, int* __restrict__ counts1,
    int2* __restrict__ entries0, int2* __restrict__ entries1)
{
    const int tid  = threadIdx.x;
    const int wave = tid >> 6;
    const int lane = tid & 63;
    const int e    = lane & 15;     // this lane's expert
    const int base = (lane >> 4) * 256;   // this lane's d-chunk

    const float rbe = rb[e];

    for (int t = 0; t < 8; ++t) {
        const int n = blockIdx.x * 32 + wave * 8 + t;
        const float* xrow = x + (size_t)n * D_DIM;

        double a0 = 0.0, a1 = 0.0, a2 = 0.0, a3 = 0.0;
        for (int i = 0; i < 256; i += 4) {
            const int d = base + i;
            a0 += (double)xrow[d + 0] * (double)rw[(d + 0) * E_NUM + e];
            a1 += (double)xrow[d + 1] * (double)rw[(d + 1) * E_NUM + e];
            a2 += (double)xrow[d + 2] * (double)rw[(d + 2) * E_NUM + e];
            a3 += (double)xrow[d + 3] * (double)rw[(d + 3) * E_NUM + e];
        }
        double v = (a0 + a1) + (a2 + a3);
        v += __shfl_xor(v, 16);
        v += __shfl_xor(v, 32);
        v += (double)rbe;          // lane L now holds logit(expert L&15)

        double lg[E_NUM];
#pragma unroll
        for (int q = 0; q < E_NUM; ++q) lg[q] = __shfl(v, q);

        // top-2 selection on fp64 logits (same comparisons as r4/r5)
        int e1 = 0;
#pragma unroll
        for (int q = 1; q < E_NUM; ++q) if (lg[q] > lg[e1]) e1 = q;
        int e2 = (e1 == 0) ? 1 : 0;
#pragma unroll
        for (int q = 0; q < E_NUM; ++q)
            if (q != e1 && lg[q] > lg[e2]) e2 = q;

        // softmax weights in fp32 (selection already fixed; w err ~1e-6)
        double m = lg[0];
#pragma unroll
        for (int q = 1; q < E_NUM; ++q) m = fmax(m, lg[q]);
        float s = 0.0f;
#pragma unroll
        for (int q = 0; q < E_NUM; ++q) s += __expf((float)(lg[q] - m));
        const float w1 = __expf((float)(lg[e1] - m)) / s;
        const float w2 = __expf((float)(lg[e2] - m)) / s;

        if (lane == 0) {
            int pos1 = atomicAdd(&counts0[e1], 1);
            if (pos1 < CAP) entries0[e1 * CAP + pos1] = make_int2(n, __float_as_int(w1));
            int pos2 = atomicAdd(&counts1[e2], 1);
            if (pos2 < CAP) entries1[e2 * CAP + pos2] = make_int2(n, __float_as_int(w2));
        }
    }
}

// ---------------- cast kernels (fast path) ---------------------------------
__global__ __launch_bounds__(256) void cast_x_kernel(
    const float* __restrict__ x, unsigned short* __restrict__ xb)
{
    const size_t i = ((size_t)blockIdx.x * 256 + threadIdx.x) * 8;
    const float4 a = *(const float4*)(x + i);
    const float4 b = *(const float4*)(x + i + 4);
    uint4 o;
    o.x = pk2bf(a.x, a.y); o.y = pk2bf(a.z, a.w);
    o.z = pk2bf(b.x, b.y); o.w = pk2bf(b.z, b.w);
    *(uint4*)(xb + i) = o;
}

// W [e][k][h] fp32 -> wt [e][h][k] bf16, 64x64 LDS tile transpose
__global__ __launch_bounds__(256) void cast_wt_kernel(
    const float* __restrict__ ew, unsigned short* __restrict__ wt)
{
    __shared__ unsigned short T[64][72];
    const int e  = blockIdx.z;
    const int k0 = blockIdx.y * 64;
    const int h0 = blockIdx.x * 64;
    const int tid = threadIdx.x;

    const int r = tid >> 4;
    const int c = (tid & 15) * 4;
#pragma unroll
    for (int it = 0; it < 4; ++it) {
        const int k = r + it * 16;
        const float4 v = *(const float4*)(ew + ((size_t)(e * 1024 + k0 + k)) * H_DIM + h0 + c);
        ushort4 p;
        p.x = f2bf(v.x); p.y = f2bf(v.y); p.z = f2bf(v.z); p.w = f2bf(v.w);
        *(ushort4*)&T[k][c] = p;
    }
    __syncthreads();

    const int h = tid >> 3;
    const int kc = (tid & 7) * 8;
#pragma unroll
    for (int it = 0; it < 2; ++it) {
        const int hh = h + it * 32;
        uint4 o;
        o.x = (unsigned int)T[kc + 0][hh] | ((unsigned int)T[kc + 1][hh] << 16);
        o.y = (unsigned int)T[kc + 2][hh] | ((unsigned int)T[kc + 3][hh] << 16);
        o.z = (unsigned int)T[kc + 4][hh] | ((unsigned int)T[kc + 5][hh] << 16);
        o.w = (unsigned int)T[kc + 6][hh] | ((unsigned int)T[kc + 7][hh] << 16);
        *(uint4*)(wt + ((size_t)(e * 1024 + h0 + hh)) * D_DIM + k0 + kc) = o;
    }
}

// ---------------- fast GEMM: 128x128 tile, BK=32, pre-cast bf16 ------------
template <bool ADD>
__global__ __launch_bounds__(256) void gemm_fast_kernel(
    const unsigned short* __restrict__ xb,   // [N][D] bf16
    const unsigned short* __restrict__ wt,   // [E][H][D] bf16 (transposed)
    const float* __restrict__ eb,
    const int* __restrict__ counts,
    const int2* __restrict__ entries,
    float* __restrict__ out)
{
    const int e = blockIdx.z;
    int count = counts[e];
    if (count > CAP) count = CAP;
    const int i0 = blockIdx.y * 128;
    if (i0 >= count) return;
    const int h0 = blockIdx.x * 128;

    __shared__ unsigned short Xs[128][KPAD];
    __shared__ unsigned short Ws[128][KPAD];
    __shared__ int   s_tok[128];
    __shared__ float s_w[128];

    const int tid = threadIdx.x;
    if (tid < 128) {
        const int i = i0 + tid;
        if (i < count) {
            int2 en = entries[e * CAP + i];
            s_tok[tid] = en.x;
            s_w[tid] = __int_as_float(en.y);
        } else {
            s_tok[tid] = 0;
            s_w[tid] = 0.0f;
        }
    }
    __syncthreads();

    const int wave = tid >> 6;
    const int lane = tid & 63;
    const int wr = (wave >> 1) * 64;
    const int wc = (wave & 1) * 64;
    const int l15 = lane & 15;
    const int quad = lane >> 4;

    f32x4 acc[4][4] = {};

    // staging map: row = tid&127, k-segment = (tid>>7)*16; two b128 each
    const int sr = tid & 127;
    const int sk = (tid >> 7) * 16;

    const unsigned short* xrow = xb + (size_t)s_tok[sr] * D_DIM + sk;
    const unsigned short* wrow = wt + ((size_t)e * H_DIM + h0 + sr) * D_DIM + sk;

    for (int d0 = 0; d0 < D_DIM; d0 += 32) {
        *(uint4*)&Xs[sr][sk]     = *(const uint4*)(xrow + d0);
        *(uint4*)&Xs[sr][sk + 8] = *(const uint4*)(xrow + d0 + 8);
        *(uint4*)&Ws[sr][sk]     = *(const uint4*)(wrow + d0);
        *(uint4*)&Ws[sr][sk + 8] = *(const uint4*)(wrow + d0 + 8);
        __syncthreads();

        bf16x8 af[4], bq[4];
#pragma unroll
        for (int i = 0; i < 4; ++i)
            af[i] = *(const bf16x8*)&Xs[wr + i * 16 + l15][quad * 8];
#pragma unroll
        for (int j = 0; j < 4; ++j)
            bq[j] = *(const bf16x8*)&Ws[wc + j * 16 + l15][quad * 8];
#pragma unroll
        for (int i = 0; i < 4; ++i)
#pragma unroll
            for (int j = 0; j < 4; ++j)
                acc[i][j] = __builtin_amdgcn_mfma_f32_16x16x32_bf16(
                    af[i], bq[j], acc[i][j], 0, 0, 0);

        __syncthreads();
    }

    float bias_j[4];
    const float* ebp = eb + e * H_DIM + h0 + wc;
#pragma unroll
    for (int j = 0; j < 4; ++j) bias_j[j] = ebp[j * 16 + l15];

#pragma unroll
    for (int i = 0; i < 4; ++i) {
#pragma unroll
        for (int r = 0; r < 4; ++r) {
            const int row = wr + i * 16 + quad * 4 + r;
            if (i0 + row < count) {
                const int tok = s_tok[row];
                const float w = s_w[row];
                float* op = out + (size_t)tok * H_DIM + h0 + wc + l15;
#pragma unroll
                for (int j = 0; j < 4; ++j) {
                    float v = w * (acc[i][j][r] + bias_j[j]);
                    if (ADD) v += op[j * 16];
                    op[j * 16] = v;
                }
            }
        }
    }
}

// ---------------- fallback GEMM (round-5, fp32 staging) --------------------
template <bool ADD>
__global__ __launch_bounds__(256) void moe_mfma_kernel(
    const float* __restrict__ x,
    const float* __restrict__ ew,
    const float* __restrict__ eb,
    const int* __restrict__ counts,
    const int2* __restrict__ entries,
    float* __restrict__ out)
{
    const int e = blockIdx.z;
    int count = counts[e];
    if (count > CAP) count = CAP;
    const int i0 = blockIdx.y * 128;
    if (i0 >= count) return;
    const int h0 = blockIdx.x * 128;

    __shared__ unsigned short Xs[128][KPAD];
    __shared__ unsigned short Ws[128][KPAD];
    __shared__ int   s_tok[128];
    __shared__ float s_w[128];

    const int tid = threadIdx.x;
    if (tid < 128) {
        const int i = i0 + tid;
        if (i < count) {
            int2 en = entries[e * CAP + i];
            s_tok[tid] = en.x;
            s_w[tid] = __int_as_float(en.y);
        } else {
            s_tok[tid] = 0;
            s_w[tid] = 0.0f;
        }
    }
    __syncthreads();

    const int wave = tid >> 6;
    const int lane = tid & 63;
    const int wr = (wave >> 1) * 64;
    const int wc = (wave & 1) * 64;
    const int l15 = lane & 15;
    const int quad = lane >> 4;

    f32x4 acc[4][4] = {};

    const int a_kq = (tid & 7) * 4;
    const int a_r0 = tid >> 3;
    const int b_n  = tid & 127;
    const int b_dh = (tid >> 7) * 16;

    const float* wcol = ew + (size_t)e * D_DIM * H_DIM + h0 + b_n;

    for (int d0 = 0; d0 < D_DIM; d0 += 32) {
#pragma unroll
        for (int it = 0; it < 4; ++it) {
            const int r = a_r0 + it * 32;
            const float4 v = *(const float4*)(x + (size_t)s_tok[r] * D_DIM + d0 + a_kq);
            ushort4 p;
            p.x = f2bf(v.x); p.y = f2bf(v.y); p.z = f2bf(v.z); p.w = f2bf(v.w);
            *(ushort4*)&Xs[r][a_kq] = p;
        }
        {
            float t[16];
#pragma unroll
            for (int i = 0; i < 16; ++i)
                t[i] = wcol[(size_t)(d0 + b_dh + i) * H_DIM];
            uint4 lo, hi;
            lo.x = pk2bf(t[0], t[1]);  lo.y = pk2bf(t[2], t[3]);
            lo.z = pk2bf(t[4], t[5]);  lo.w = pk2bf(t[6], t[7]);
            hi.x = pk2bf(t[8], t[9]);  hi.y = pk2bf(t[10], t[11]);
            hi.z = pk2bf(t[12], t[13]); hi.w = pk2bf(t[14], t[15]);
            *(uint4*)&Ws[b_n][b_dh]     = lo;
            *(uint4*)&Ws[b_n][b_dh + 8] = hi;
        }
        __syncthreads();

        bf16x8 af[4], bq[4];
#pragma unroll
        for (int i = 0; i < 4; ++i)
            af[i] = *(const bf16x8*)&Xs[wr + i * 16 + l15][quad * 8];
#pragma unroll
        for (int j = 0; j < 4; ++j)
            bq[j] = *(const bf16x8*)&Ws[wc + j * 16 + l15][quad * 8];
#pragma unroll
        for (int i = 0; i < 4; ++i)
#pragma unroll
            for (int j = 0; j < 4; ++j)
                acc[i][j] = __builtin_amdgcn_mfma_f32_16x16x32_bf16(
                    af[i], bq[j], acc[i][j], 0, 0, 0);

        __syncthreads();
    }

    float bias_j[4];
    const float* ebp = eb + e * H_DIM + h0 + wc;
#pragma unroll
    for (int j = 0; j < 4; ++j) bias_j[j] = ebp[j * 16 + l15];

#pragma unroll
    for (int i = 0; i < 4; ++i) {
#pragma unroll
        for (int r = 0; r < 4; ++r) {
            const int row = wr + i * 16 + quad * 4 + r;
            if (i0 + row < count) {
                const int tok = s_tok[row];
                const float w = s_w[row];
                float* op = out + (size_t)tok * H_DIM + h0 + wc + l15;
#pragma unroll
                for (int j = 0; j < 4; ++j) {
                    float v = w * (acc[i][j][r] + bias_j[j]);
                    if (ADD) v += op[j * 16];
                    op[j * 16] = v;
                }
            }
        }
    }
}

extern "C" void kernel_launch(void* const* d_in, const int* in_sizes, int n_in,
                              void* d_out, int out_size, void* d_ws, size_t ws_size,
                              hipStream_t stream)
{
    const float* x  = (const float*)d_in[0];
    const float* rw = (const float*)d_in[1];
    const float* rb = (const float*)d_in[2];
    const float* ew = (const float*)d_in[3];
    const float* eb = (const float*)d_in[4];

    char* ws = (char*)d_ws;
    int*  counts0  = (int*)ws;
    int*  counts1  = (int*)(ws + 64);
    int2* entries0 = (int2*)(ws + 1024);
    int2* entries1 = (int2*)(ws + 1024 + E_NUM * CAP * 8);
    unsigned short* xb = (unsigned short*)(ws + (1u << 20));    // 16.78 MB
    unsigned short* wt = (unsigned short*)(ws + (20u << 20));   // 33.55 MB

    const bool fast = ws_size >= (56u << 20);   // host-constant, graph-safe

    hipMemsetAsync(ws, 0, 128, stream);

    router_kernel<<<N_TOK / 32, 256, 0, stream>>>(x, rw, rb, counts0, counts1,
                                                  entries0, entries1);

    if (fast) {
        cast_x_kernel<<<(N_TOK * D_DIM / 8) / 256, 256, 0, stream>>>(x, xb);
        dim3 cg(H_DIM / 64, D_DIM / 64, E_NUM);
        cast_wt_kernel<<<cg, 256, 0, stream>>>(ew, wt);

        dim3 grid(H_DIM / 128, CAP / 128, E_NUM);
        gemm_fast_kernel<false><<<grid, 256, 0, stream>>>(
            xb, wt, eb, counts0, entries0, (float*)d_out);
        gemm_fast_kernel<true><<<grid, 256, 0, stream>>>(
            xb, wt, eb, counts1, entries1, (float*)d_out);
    } else {
        dim3 grid(H_DIM / 128, CAP / 128, E_NUM);
        moe_mfma_kernel<false><<<grid, 256, 0, stream>>>(
            x, ew, eb, counts0, entries0, (float*)d_out);
        moe_mfma_kernel<true><<<grid, 256, 0, stream>>>(
            x, ew, eb, counts1, entries1, (float*)d_out);
    }
}

// Round 8
// 420.506 us; speedup vs baseline: 1.3234x; 1.3234x over previous
//
#include <hip/hip_runtime.h>
#include <hip/hip_bf16.h>

// MoE block: N=8192, D=1024, H=1024, E=16, top-k=2. Inputs fp32, output fp32.
// out[n] = w1*(x@W_e1 + b_e1) + w2*(x@W_e2 + b_e2), w = top-2 of softmax.
//
// Round-8:
//  * router: r7's register-coalesced fp64 scheme, but 1 token/wave and 2048
//    blocks -> 8 waves/SIMD (r7 had 1 wave/SIMD -> 277us latency-bound).
//  * GEMM fast path: 128x128 tile, BK=64 (16 k-iters, half the barriers),
//    KPAD=72 (2-way bank aliasing only), staging from pre-cast bf16 xb/wt.
//  * fallback (ws < 56 MB): r5 fp32-staging MFMA kernel, unchanged.

#define N_TOK 8192
#define D_DIM 1024
#define H_DIM 1024
#define E_NUM 16
#define CAP   1024
#define KPAD  40    // fallback LDS row stride (ushorts)
#define KP2   72    // fast-kernel LDS row stride (ushorts, 144 B = 9*16 B)

typedef __attribute__((ext_vector_type(4))) float f32x4;
typedef __attribute__((ext_vector_type(8))) short bf16x8;

__device__ __forceinline__ unsigned short f2bf(float f) {
    unsigned int u = __float_as_uint(f);
    unsigned int r = u + 0x7fffu + ((u >> 16) & 1u);   // RNE
    return (unsigned short)(r >> 16);
}
__device__ __forceinline__ unsigned int pk2bf(float lo, float hi) {
    return (unsigned int)f2bf(lo) | ((unsigned int)f2bf(hi) << 16);
}

// ---------------- router: 2048 blocks x 256 thr, 1 token/wave --------------
__global__ __launch_bounds__(256) void router_kernel(
    const float* __restrict__ x,
    const float* __restrict__ rw,
    const float* __restrict__ rb,
    int* __restrict__ counts0, int* __restrict__ counts1,
    int2* __restrict__ entries0, int2* __restrict__ entries1)
{
    const int tid  = threadIdx.x;
    const int wave = tid >> 6;
    const int lane = tid & 63;
    const int e    = lane & 15;           // this lane's expert
    const int base = (lane >> 4) * 256;   // this lane's d-chunk

    const float rbe = rb[e];
    const int n = blockIdx.x * 4 + wave;
    const float* xrow = x + (size_t)n * D_DIM;

    double a0 = 0.0, a1 = 0.0, a2 = 0.0, a3 = 0.0;
    for (int i = 0; i < 256; i += 4) {
        const int d = base + i;
        a0 += (double)xrow[d + 0] * (double)rw[(d + 0) * E_NUM + e];
        a1 += (double)xrow[d + 1] * (double)rw[(d + 1) * E_NUM + e];
        a2 += (double)xrow[d + 2] * (double)rw[(d + 2) * E_NUM + e];
        a3 += (double)xrow[d + 3] * (double)rw[(d + 3) * E_NUM + e];
    }
    double v = (a0 + a1) + (a2 + a3);
    v += __shfl_xor(v, 16);
    v += __shfl_xor(v, 32);
    v += (double)rbe;                     // lane L holds logit(expert L&15)

    double lg[E_NUM];
#pragma unroll
    for (int q = 0; q < E_NUM; ++q) lg[q] = __shfl(v, q);

    // top-2 selection on fp64 logits (same comparisons as r4/r5)
    int e1 = 0;
#pragma unroll
    for (int q = 1; q < E_NUM; ++q) if (lg[q] > lg[e1]) e1 = q;
    int e2 = (e1 == 0) ? 1 : 0;
#pragma unroll
    for (int q = 0; q < E_NUM; ++q)
        if (q != e1 && lg[q] > lg[e2]) e2 = q;

    // softmax weights in fp32 (selection already fixed; w err ~1e-6)
    double m = lg[0];
#pragma unroll
    for (int q = 1; q < E_NUM; ++q) m = fmax(m, lg[q]);
    float s = 0.0f;
#pragma unroll
    for (int q = 0; q < E_NUM; ++q) s += __expf((float)(lg[q] - m));
    const float w1 = __expf((float)(lg[e1] - m)) / s;
    const float w2 = __expf((float)(lg[e2] - m)) / s;

    if (lane == 0) {
        int pos1 = atomicAdd(&counts0[e1], 1);
        if (pos1 < CAP) entries0[e1 * CAP + pos1] = make_int2(n, __float_as_int(w1));
        int pos2 = atomicAdd(&counts1[e2], 1);
        if (pos2 < CAP) entries1[e2 * CAP + pos2] = make_int2(n, __float_as_int(w2));
    }
}

// ---------------- cast kernels (fast path) ---------------------------------
__global__ __launch_bounds__(256) void cast_x_kernel(
    const float* __restrict__ x, unsigned short* __restrict__ xb)
{
    const size_t i = ((size_t)blockIdx.x * 256 + threadIdx.x) * 8;
    const float4 a = *(const float4*)(x + i);
    const float4 b = *(const float4*)(x + i + 4);
    uint4 o;
    o.x = pk2bf(a.x, a.y); o.y = pk2bf(a.z, a.w);
    o.z = pk2bf(b.x, b.y); o.w = pk2bf(b.z, b.w);
    *(uint4*)(xb + i) = o;
}

// W [e][k][h] fp32 -> wt [e][h][k] bf16, 64x64 LDS tile transpose
__global__ __launch_bounds__(256) void cast_wt_kernel(
    const float* __restrict__ ew, unsigned short* __restrict__ wt)
{
    __shared__ unsigned short T[64][72];
    const int e  = blockIdx.z;
    const int k0 = blockIdx.y * 64;
    const int h0 = blockIdx.x * 64;
    const int tid = threadIdx.x;

    const int r = tid >> 4;
    const int c = (tid & 15) * 4;
#pragma unroll
    for (int it = 0; it < 4; ++it) {
        const int k = r + it * 16;
        const float4 v = *(const float4*)(ew + ((size_t)(e * 1024 + k0 + k)) * H_DIM + h0 + c);
        ushort4 p;
        p.x = f2bf(v.x); p.y = f2bf(v.y); p.z = f2bf(v.z); p.w = f2bf(v.w);
        *(ushort4*)&T[k][c] = p;
    }
    __syncthreads();

    const int h = tid >> 3;
    const int kc = (tid & 7) * 8;
#pragma unroll
    for (int it = 0; it < 2; ++it) {
        const int hh = h + it * 32;
        uint4 o;
        o.x = (unsigned int)T[kc + 0][hh] | ((unsigned int)T[kc + 1][hh] << 16);
        o.y = (unsigned int)T[kc + 2][hh] | ((unsigned int)T[kc + 3][hh] << 16);
        o.z = (unsigned int)T[kc + 4][hh] | ((unsigned int)T[kc + 5][hh] << 16);
        o.w = (unsigned int)T[kc + 6][hh] | ((unsigned int)T[kc + 7][hh] << 16);
        *(uint4*)(wt + ((size_t)(e * 1024 + h0 + hh)) * D_DIM + k0 + kc) = o;
    }
}

// ---------------- fast GEMM: 128x128 tile, BK=64, pre-cast bf16 ------------
template <bool ADD>
__global__ __launch_bounds__(256) void gemm_fast_kernel(
    const unsigned short* __restrict__ xb,   // [N][D] bf16
    const unsigned short* __restrict__ wt,   // [E][H][D] bf16 (transposed)
    const float* __restrict__ eb,
    const int* __restrict__ counts,
    const int2* __restrict__ entries,
    float* __restrict__ out)
{
    const int e = blockIdx.z;
    int count = counts[e];
    if (count > CAP) count = CAP;
    const int i0 = blockIdx.y * 128;
    if (i0 >= count) return;
    const int h0 = blockIdx.x * 128;

    __shared__ unsigned short Xs[128][KP2];
    __shared__ unsigned short Ws[128][KP2];
    __shared__ int   s_tok[128];
    __shared__ float s_w[128];

    const int tid = threadIdx.x;
    if (tid < 128) {
        const int i = i0 + tid;
        if (i < count) {
            int2 en = entries[e * CAP + i];
            s_tok[tid] = en.x;
            s_w[tid] = __int_as_float(en.y);
        } else {
            s_tok[tid] = 0;
            s_w[tid] = 0.0f;
        }
    }
    __syncthreads();

    const int wave = tid >> 6;
    const int lane = tid & 63;
    const int wr = (wave >> 1) * 64;
    const int wc = (wave & 1) * 64;
    const int l15 = lane & 15;
    const int quad = lane >> 4;

    f32x4 acc[4][4] = {};

    // staging map: row = tid&127, k-half = (tid>>7)*32 ushorts; 4 b128 each
    const int sr = tid & 127;
    const int sk = (tid >> 7) * 32;

    const unsigned short* xrow = xb + (size_t)s_tok[sr] * D_DIM + sk;
    const unsigned short* wrow = wt + ((size_t)e * H_DIM + h0 + sr) * D_DIM + sk;

    for (int d0 = 0; d0 < D_DIM; d0 += 64) {
        *(uint4*)&Xs[sr][sk]      = *(const uint4*)(xrow + d0);
        *(uint4*)&Xs[sr][sk + 8]  = *(const uint4*)(xrow + d0 + 8);
        *(uint4*)&Xs[sr][sk + 16] = *(const uint4*)(xrow + d0 + 16);
        *(uint4*)&Xs[sr][sk + 24] = *(const uint4*)(xrow + d0 + 24);
        *(uint4*)&Ws[sr][sk]      = *(const uint4*)(wrow + d0);
        *(uint4*)&Ws[sr][sk + 8]  = *(const uint4*)(wrow + d0 + 8);
        *(uint4*)&Ws[sr][sk + 16] = *(const uint4*)(wrow + d0 + 16);
        *(uint4*)&Ws[sr][sk + 24] = *(const uint4*)(wrow + d0 + 24);
        __syncthreads();

#pragma unroll
        for (int ks = 0; ks < 2; ++ks) {
            bf16x8 af[4], bq[4];
#pragma unroll
            for (int i = 0; i < 4; ++i)
                af[i] = *(const bf16x8*)&Xs[wr + i * 16 + l15][ks * 32 + quad * 8];
#pragma unroll
            for (int j = 0; j < 4; ++j)
                bq[j] = *(const bf16x8*)&Ws[wc + j * 16 + l15][ks * 32 + quad * 8];
#pragma unroll
            for (int i = 0; i < 4; ++i)
#pragma unroll
                for (int j = 0; j < 4; ++j)
                    acc[i][j] = __builtin_amdgcn_mfma_f32_16x16x32_bf16(
                        af[i], bq[j], acc[i][j], 0, 0, 0);
        }
        __syncthreads();
    }

    float bias_j[4];
    const float* ebp = eb + e * H_DIM + h0 + wc;
#pragma unroll
    for (int j = 0; j < 4; ++j) bias_j[j] = ebp[j * 16 + l15];

#pragma unroll
    for (int i = 0; i < 4; ++i) {
#pragma unroll
        for (int r = 0; r < 4; ++r) {
            const int row = wr + i * 16 + quad * 4 + r;
            if (i0 + row < count) {
                const int tok = s_tok[row];
                const float w = s_w[row];
                float* op = out + (size_t)tok * H_DIM + h0 + wc + l15;
#pragma unroll
                for (int j = 0; j < 4; ++j) {
                    float v = w * (acc[i][j][r] + bias_j[j]);
                    if (ADD) v += op[j * 16];
                    op[j * 16] = v;
                }
            }
        }
    }
}

// ---------------- fallback GEMM (round-5, fp32 staging) --------------------
template <bool ADD>
__global__ __launch_bounds__(256) void moe_mfma_kernel(
    const float* __restrict__ x,
    const float* __restrict__ ew,
    const float* __restrict__ eb,
    const int* __restrict__ counts,
    const int2* __restrict__ entries,
    float* __restrict__ out)
{
    const int e = blockIdx.z;
    int count = counts[e];
    if (count > CAP) count = CAP;
    const int i0 = blockIdx.y * 128;
    if (i0 >= count) return;
    const int h0 = blockIdx.x * 128;

    __shared__ unsigned short Xs[128][KPAD];
    __shared__ unsigned short Ws[128][KPAD];
    __shared__ int   s_tok[128];
    __shared__ float s_w[128];

    const int tid = threadIdx.x;
    if (tid < 128) {
        const int i = i0 + tid;
        if (i < count) {
            int2 en = entries[e * CAP + i];
            s_tok[tid] = en.x;
            s_w[tid] = __int_as_float(en.y);
        } else {
            s_tok[tid] = 0;
            s_w[tid] = 0.0f;
        }
    }
    __syncthreads();

    const int wave = tid >> 6;
    const int lane = tid & 63;
    const int wr = (wave >> 1) * 64;
    const int wc = (wave & 1) * 64;
    const int l15 = lane & 15;
    const int quad = lane >> 4;

    f32x4 acc[4][4] = {};

    const int a_kq = (tid & 7) * 4;
    const int a_r0 = tid >> 3;
    const int b_n  = tid & 127;
    const int b_dh = (tid >> 7) * 16;

    const float* wcol = ew + (size_t)e * D_DIM * H_DIM + h0 + b_n;

    for (int d0 = 0; d0 < D_DIM; d0 += 32) {
#pragma unroll
        for (int it = 0; it < 4; ++it) {
            const int r = a_r0 + it * 32;
            const float4 v = *(const float4*)(x + (size_t)s_tok[r] * D_DIM + d0 + a_kq);
            ushort4 p;
            p.x = f2bf(v.x); p.y = f2bf(v.y); p.z = f2bf(v.z); p.w = f2bf(v.w);
            *(ushort4*)&Xs[r][a_kq] = p;
        }
        {
            float t[16];
#pragma unroll
            for (int i = 0; i < 16; ++i)
                t[i] = wcol[(size_t)(d0 + b_dh + i) * H_DIM];
            uint4 lo, hi;
            lo.x = pk2bf(t[0], t[1]);  lo.y = pk2bf(t[2], t[3]);
            lo.z = pk2bf(t[4], t[5]);  lo.w = pk2bf(t[6], t[7]);
            hi.x = pk2bf(t[8], t[9]);  hi.y = pk2bf(t[10], t[11]);
            hi.z = pk2bf(t[12], t[13]); hi.w = pk2bf(t[14], t[15]);
            *(uint4*)&Ws[b_n][b_dh]     = lo;
            *(uint4*)&Ws[b_n][b_dh + 8] = hi;
        }
        __syncthreads();

        bf16x8 af[4], bq[4];
#pragma unroll
        for (int i = 0; i < 4; ++i)
            af[i] = *(const bf16x8*)&Xs[wr + i * 16 + l15][quad * 8];
#pragma unroll
        for (int j = 0; j < 4; ++j)
            bq[j] = *(const bf16x8*)&Ws[wc + j * 16 + l15][quad * 8];
#pragma unroll
        for (int i = 0; i < 4; ++i)
#pragma unroll
            for (int j = 0; j < 4; ++j)
                acc[i][j] = __builtin_amdgcn_mfma_f32_16x16x32_bf16(
                    af[i], bq[j], acc[i][j], 0, 0, 0);

        __syncthreads();
    }

    float bias_j[4];
    const float* ebp = eb + e * H_DIM + h0 + wc;
#pragma unroll
    for (int j = 0; j < 4; ++j) bias_j[j] = ebp[j * 16 + l15];

#pragma unroll
    for (int i = 0; i < 4; ++i) {
#pragma unroll
        for (int r = 0; r < 4; ++r) {
            const int row = wr + i * 16 + quad * 4 + r;
            if (i0 + row < count) {
                const int tok = s_tok[row];
                const float w = s_w[row];
                float* op = out + (size_t)tok * H_DIM + h0 + wc + l15;
#pragma unroll
                for (int j = 0; j < 4; ++j) {
                    float v = w * (acc[i][j][r] + bias_j[j]);
                    if (ADD) v += op[j * 16];
                    op[j * 16] = v;
                }
            }
        }
    }
}

extern "C" void kernel_launch(void* const* d_in, const int* in_sizes, int n_in,
                              void* d_out, int out_size, void* d_ws, size_t ws_size,
                              hipStream_t stream)
{
    const float* x  = (const float*)d_in[0];
    const float* rw = (const float*)d_in[1];
    const float* rb = (const float*)d_in[2];
    const float* ew = (const float*)d_in[3];
    const float* eb = (const float*)d_in[4];

    char* ws = (char*)d_ws;
    int*  counts0  = (int*)ws;
    int*  counts1  = (int*)(ws + 64);
    int2* entries0 = (int2*)(ws + 1024);
    int2* entries1 = (int2*)(ws + 1024 + E_NUM * CAP * 8);
    unsigned short* xb = (unsigned short*)(ws + (1u << 20));    // 16.78 MB
    unsigned short* wt = (unsigned short*)(ws + (20u << 20));   // 33.55 MB

    const bool fast = ws_size >= (56u << 20);   // host-constant, graph-safe

    hipMemsetAsync(ws, 0, 128, stream);

    router_kernel<<<N_TOK / 4, 256, 0, stream>>>(x, rw, rb, counts0, counts1,
                                                 entries0, entries1);

    if (fast) {
        cast_x_kernel<<<(N_TOK * D_DIM / 8) / 256, 256, 0, stream>>>(x, xb);
        dim3 cg(H_DIM / 64, D_DIM / 64, E_NUM);
        cast_wt_kernel<<<cg, 256, 0, stream>>>(ew, wt);

        dim3 grid(H_DIM / 128, CAP / 128, E_NUM);
        gemm_fast_kernel<false><<<grid, 256, 0, stream>>>(
            xb, wt, eb, counts0, entries0, (float*)d_out);
        gemm_fast_kernel<true><<<grid, 256, 0, stream>>>(
            xb, wt, eb, counts1, entries1, (float*)d_out);
    } else {
        dim3 grid(H_DIM / 128, CAP / 128, E_NUM);
        moe_mfma_kernel<false><<<grid, 256, 0, stream>>>(
            x, ew, eb, counts0, entries0, (float*)d_out);
        moe_mfma_kernel<true><<<grid, 256, 0, stream>>>(
            x, ew, eb, counts1, entries1, (float*)d_out);
    }
}